// Round 13
// baseline (178.510 us; speedup 1.0000x reference)
//
#include <hip/hip_runtime.h>

// SNN classifier: T=500, B=256, 96 -> 64 -> 80, leaky (subtract reset).
// f32 BLAS-order arithmetic replicated exactly (single-accumulator
// k-ascending __fmaf_rn chains; fixed leaky op-sequence) -> outputs
// bitwise-identical to the passing round-2..12 kernels.
//
// Round-13: round-12's P=4 regressed (K3 67us, Occupancy 10%): bigger
// serial chains + 55-57KB LDS capping residency at 1-2 blocks/CU ->
// LDS-LATENCY-bound with nothing to hide ~120cyc ds_read latency.
// Fix: round-11 structure (known 103us) with LDS < 40KB/block via
// k-halved x staging -> 4 blocks/CU (16 waves/CU):
//   K1: W1 24.6KB + x[64][52] 13.3KB = 37.9KB (52==20 mod 32, optimal
//       8-phase b128). P=1.
//   K3: W2 20.5KB + 2x spk[64][36] 18.4KB = 38.9KB (36==4 mod 32). P=2.
// __launch_bounds__(256,4) keeps VGPR<=128 so 4 waves/SIMD stick.
// k ascends across halves -> identical FP chains. K2/K4 untouched.

#define T_STEPS 500
#define BATCH   256
#define N_IN    96
#define N_HID   64
#define N_OUT   80
#define CH      50    // chunk size in K2/K4 (500 = 10*50)

// ---------------- K1: cur1 = x @ W1 + b1 ----------------
// grid 500*4, block 256 (4 waves = 4 16-h slices). Block = (t, 64-b group).
__global__ __launch_bounds__(256, 4) void k1_cur1(
    const float* __restrict__ x,   // (T,B,96)
    const float* __restrict__ W1,  // (96,64)
    const float* __restrict__ b1,  // (64)
    float* __restrict__ cur1)      // (T,B,64) region inside outs
{
    const int t    = blockIdx.x >> 2;
    const int b0   = (blockIdx.x & 3) << 6;
    const int lane = threadIdx.x & 63;   // = local b
    const int w    = threadIdx.x >> 6;   // wave id = h-quarter
    const int o0   = w << 4;

    __shared__ float ws[96 * 64];        // W1 [k][h]   24.6 KB
    __shared__ float xs[64 * 52];        // x k-half    13.3 KB (stride 52)

    // ---- stage W1 (coalesced, linear) + x k-half 0
    {
        const float4* __restrict__ srcw = reinterpret_cast<const float4*>(W1);
        #pragma unroll
        for (int ii = 0; ii < 6; ++ii) {
            const int i = ii * 256 + threadIdx.x;
            *reinterpret_cast<float4*>(&ws[i * 4]) = srcw[i];
        }
        #pragma unroll
        for (int ii = 0; ii < 3; ++ii) {
            const int i   = ii * 256 + threadIdx.x;   // 768 granules
            const int row = i / 12, g = i % 12;
            const float4 v = *reinterpret_cast<const float4*>(
                x + ((size_t)t * BATCH + b0 + row) * N_IN + g * 4);
            *reinterpret_cast<float4*>(&xs[row * 52 + g * 4]) = v;
        }
    }
    __syncthreads();

    float acc[16];
    #pragma unroll
    for (int o = 0; o < 16; ++o) acc[o] = 0.0f;

    #pragma unroll 1
    for (int kh = 0; kh < 2; ++kh) {     // two 48-k halves, k ascending
        #pragma unroll
        for (int kg = 0; kg < 12; ++kg) {
            const float4 xv = *reinterpret_cast<const float4*>(
                &xs[lane * 52 + kg * 4]);
            const float xq[4] = {xv.x, xv.y, xv.z, xv.w};
            #pragma unroll
            for (int j = 0; j < 4; ++j) {
                const int k = kh * 48 + kg * 4 + j;
                const float4* __restrict__ wr =       // LDS broadcast
                    reinterpret_cast<const float4*>(&ws[k * 64 + o0]);
                const float4 w0 = wr[0], w1 = wr[1], w2 = wr[2], w3 = wr[3];
                const float wv[16] = {w0.x, w0.y, w0.z, w0.w,
                                      w1.x, w1.y, w1.z, w1.w,
                                      w2.x, w2.y, w2.z, w2.w,
                                      w3.x, w3.y, w3.z, w3.w};
                const float xsc = xq[j];
                #pragma unroll
                for (int o = 0; o < 16; ++o)
                    acc[o] = __fmaf_rn(xsc, wv[o], acc[o]);
            }
        }
        if (kh == 0) {                   // swap in k-half 1
            __syncthreads();             // all lanes done reading xs
            #pragma unroll
            for (int ii = 0; ii < 3; ++ii) {
                const int i   = ii * 256 + threadIdx.x;
                const int row = i / 12, g = i % 12;
                const float4 v = *reinterpret_cast<const float4*>(
                    x + ((size_t)t * BATCH + b0 + row) * N_IN + 48 + g * 4);
                *reinterpret_cast<float4*>(&xs[row * 52 + g * 4]) = v;
            }
            __syncthreads();
        }
    }

    // ---- bias + direct per-lane stores (wave w covers one 64B line/row)
    float* dst = cur1 + ((size_t)t * BATCH + b0 + lane) * N_HID + o0;
    #pragma unroll
    for (int o4 = 0; o4 < 4; ++o4) {
        float4 v;
        v.x = __fadd_rn(acc[o4 * 4 + 0], b1[o0 + o4 * 4 + 0]);
        v.y = __fadd_rn(acc[o4 * 4 + 1], b1[o0 + o4 * 4 + 1]);
        v.z = __fadd_rn(acc[o4 * 4 + 2], b1[o0 + o4 * 4 + 2]);
        v.w = __fadd_rn(acc[o4 * 4 + 3], b1[o0 + o4 * 4 + 3]);
        reinterpret_cast<float4*>(dst)[o4] = v;
    }
}

// ---------------- K2: layer-1 recurrence (in-place cur1 -> spk) ----------------
__global__ __launch_bounds__(64) void k2_rec1(float* cs)  // outs region
{
    const int b = blockIdx.x;
    const int h = threadIdx.x;
    const size_t str  = (size_t)BATCH * N_HID;
    const size_t base = (size_t)b * N_HID + h;

    float A[CH], Bv[CH];
    #pragma unroll
    for (int i = 0; i < CH; ++i) A[i] = cs[(size_t)i * str + base];

    float mem = 0.f, s = 0.f;
    for (int cp = 0; cp < 5; ++cp) {            // 10 chunks, processed in pairs
        const int c0 = 2 * cp;
        #pragma unroll
        for (int i = 0; i < CH; ++i)            // prefetch chunk c0+1
            Bv[i] = cs[(size_t)((c0 + 1) * CH + i) * str + base];
        #pragma unroll
        for (int i = 0; i < CH; ++i) {          // compute chunk c0 from A
            const float m = __fsub_rn(__fadd_rn(__fmul_rn(0.95f, mem), A[i]), s);
            mem = m; s = (m > 1.0f) ? 1.0f : 0.0f;
            cs[(size_t)(c0 * CH + i) * str + base] = s;
        }
        if (cp < 4) {
            #pragma unroll
            for (int i = 0; i < CH; ++i)        // prefetch chunk c0+2
                A[i] = cs[(size_t)((c0 + 2) * CH + i) * str + base];
        }
        #pragma unroll
        for (int i = 0; i < CH; ++i) {          // compute chunk c0+1 from Bv
            const float m = __fsub_rn(__fadd_rn(__fmul_rn(0.95f, mem), Bv[i]), s);
            mem = m; s = (m > 1.0f) ? 1.0f : 0.0f;
            cs[(size_t)((c0 + 1) * CH + i) * str + base] = s;
        }
    }
}

// ---------------- K3: cur2 = spk @ W2 + b2 ----------------
// grid 250*4, block 256 (4 waves = 4 20-o slices). Block = (t-pair, 64-b).
__global__ __launch_bounds__(256, 4) void k3_cur2(
    const float* __restrict__ spk,  // (T,B,64) in outs
    const float* __restrict__ W2,   // (64,80)
    const float* __restrict__ b2,   // (80)
    float* __restrict__ cur2)       // (T,B,80) = outm region
{
    const int tp   = blockIdx.x >> 2;
    const int b0   = (blockIdx.x & 3) << 6;
    const int t0   = tp * 2;
    const int lane = threadIdx.x & 63;   // = local b
    const int w    = threadIdx.x >> 6;   // wave id
    const int o0   = w * 20;

    __shared__ float ws[64 * 80];        // W2 [k][o]       20.5 KB
    __shared__ float xs0[64 * 36];       // spk t0 k-half    9.2 KB (stride 36)
    __shared__ float xs1[64 * 36];       // spk t0+1 k-half  9.2 KB

    // ---- stage W2 + spk k-half 0 of both t's
    {
        const float4* __restrict__ srcw = reinterpret_cast<const float4*>(W2);
        #pragma unroll
        for (int ii = 0; ii < 5; ++ii) {
            const int i = ii * 256 + threadIdx.x;
            *reinterpret_cast<float4*>(&ws[i * 4]) = srcw[i];
        }
        #pragma unroll
        for (int ii = 0; ii < 2; ++ii) {
            const int i   = ii * 256 + threadIdx.x;   // 512 granules per t
            const int row = i >> 3, g = i & 7;
            const float4 v0 = *reinterpret_cast<const float4*>(
                spk + ((size_t)t0 * BATCH + b0 + row) * N_HID + g * 4);
            const float4 v1 = *reinterpret_cast<const float4*>(
                spk + ((size_t)(t0 + 1) * BATCH + b0 + row) * N_HID + g * 4);
            *reinterpret_cast<float4*>(&xs0[row * 36 + g * 4]) = v0;
            *reinterpret_cast<float4*>(&xs1[row * 36 + g * 4]) = v1;
        }
    }
    __syncthreads();

    float acc0[20], acc1[20];
    #pragma unroll
    for (int o = 0; o < 20; ++o) { acc0[o] = 0.0f; acc1[o] = 0.0f; }

    #pragma unroll 1
    for (int kh = 0; kh < 2; ++kh) {     // two 32-k halves, k ascending
        #pragma unroll
        for (int kg = 0; kg < 8; ++kg) {
            const float4 xv0 = *reinterpret_cast<const float4*>(
                &xs0[lane * 36 + kg * 4]);
            const float4 xv1 = *reinterpret_cast<const float4*>(
                &xs1[lane * 36 + kg * 4]);
            const float xq0[4] = {xv0.x, xv0.y, xv0.z, xv0.w};
            const float xq1[4] = {xv1.x, xv1.y, xv1.z, xv1.w};
            #pragma unroll
            for (int j = 0; j < 4; ++j) {
                const int k = kh * 32 + kg * 4 + j;
                const float4* __restrict__ wr =       // LDS broadcast
                    reinterpret_cast<const float4*>(&ws[k * 80 + o0]);
                const float4 w0 = wr[0], w1 = wr[1], w2 = wr[2], w3 = wr[3], w4 = wr[4];
                const float wv[20] = {w0.x, w0.y, w0.z, w0.w,
                                      w1.x, w1.y, w1.z, w1.w,
                                      w2.x, w2.y, w2.z, w2.w,
                                      w3.x, w3.y, w3.z, w3.w,
                                      w4.x, w4.y, w4.z, w4.w};
                const float a = xq0[j], b = xq1[j];
                #pragma unroll
                for (int o = 0; o < 20; ++o) {
                    acc0[o] = __fmaf_rn(a, wv[o], acc0[o]);
                    acc1[o] = __fmaf_rn(b, wv[o], acc1[o]);
                }
            }
        }
        if (kh == 0) {                   // swap in k-half 1
            __syncthreads();
            #pragma unroll
            for (int ii = 0; ii < 2; ++ii) {
                const int i   = ii * 256 + threadIdx.x;
                const int row = i >> 3, g = i & 7;
                const float4 v0 = *reinterpret_cast<const float4*>(
                    spk + ((size_t)t0 * BATCH + b0 + row) * N_HID + 32 + g * 4);
                const float4 v1 = *reinterpret_cast<const float4*>(
                    spk + ((size_t)(t0 + 1) * BATCH + b0 + row) * N_HID + 32 + g * 4);
                *reinterpret_cast<float4*>(&xs0[row * 36 + g * 4]) = v0;
                *reinterpret_cast<float4*>(&xs1[row * 36 + g * 4]) = v1;
            }
            __syncthreads();
        }
    }

    // ---- bias + direct per-lane stores for both t's
    float* d0 = cur2 + ((size_t)t0 * BATCH + b0 + lane) * N_OUT + o0;
    float* d1 = cur2 + ((size_t)(t0 + 1) * BATCH + b0 + lane) * N_OUT + o0;
    #pragma unroll
    for (int o4 = 0; o4 < 5; ++o4) {
        float4 v0, v1;
        v0.x = __fadd_rn(acc0[o4 * 4 + 0], b2[o0 + o4 * 4 + 0]);
        v0.y = __fadd_rn(acc0[o4 * 4 + 1], b2[o0 + o4 * 4 + 1]);
        v0.z = __fadd_rn(acc0[o4 * 4 + 2], b2[o0 + o4 * 4 + 2]);
        v0.w = __fadd_rn(acc0[o4 * 4 + 3], b2[o0 + o4 * 4 + 3]);
        v1.x = __fadd_rn(acc1[o4 * 4 + 0], b2[o0 + o4 * 4 + 0]);
        v1.y = __fadd_rn(acc1[o4 * 4 + 1], b2[o0 + o4 * 4 + 1]);
        v1.z = __fadd_rn(acc1[o4 * 4 + 2], b2[o0 + o4 * 4 + 2]);
        v1.w = __fadd_rn(acc1[o4 * 4 + 3], b2[o0 + o4 * 4 + 3]);
        reinterpret_cast<float4*>(d0)[o4] = v0;
        reinterpret_cast<float4*>(d1)[o4] = v1;
    }
}

// ---------------- K4: layer-2 recurrence (cur2 in outm -> spk/mem finals) ----------------
__global__ __launch_bounds__(80) void k4_rec2(float* cm, float* os)
{
    const int b = blockIdx.x;
    const int o = threadIdx.x;   // 0..79
    const size_t str  = (size_t)BATCH * N_OUT;
    const size_t base = (size_t)b * N_OUT + o;

    float A[CH], Bv[CH];
    #pragma unroll
    for (int i = 0; i < CH; ++i) A[i] = cm[(size_t)i * str + base];

    float mem = 0.f, s = 0.f;
    for (int cp = 0; cp < 5; ++cp) {
        const int c0 = 2 * cp;
        #pragma unroll
        for (int i = 0; i < CH; ++i)
            Bv[i] = cm[(size_t)((c0 + 1) * CH + i) * str + base];
        #pragma unroll
        for (int i = 0; i < CH; ++i) {
            const int t = c0 * CH + i;
            const float m = __fsub_rn(__fadd_rn(__fmul_rn(0.95f, mem), A[i]), s);
            mem = m; s = (m > 1.0f) ? 1.0f : 0.0f;
            os[(size_t)t * str + base] = s;
            cm[(size_t)t * str + base] = m;
        }
        if (cp < 4) {
            #pragma unroll
            for (int i = 0; i < CH; ++i)
                A[i] = cm[(size_t)((c0 + 2) * CH + i) * str + base];
        }
        #pragma unroll
        for (int i = 0; i < CH; ++i) {
            const int t = (c0 + 1) * CH + i;
            const float m = __fsub_rn(__fadd_rn(__fmul_rn(0.95f, mem), Bv[i]), s);
            mem = m; s = (m > 1.0f) ? 1.0f : 0.0f;
            os[(size_t)t * str + base] = s;
            cm[(size_t)t * str + base] = m;
        }
    }
}

extern "C" void kernel_launch(void* const* d_in, const int* in_sizes, int n_in,
                              void* d_out, int out_size, void* d_ws, size_t ws_size,
                              hipStream_t stream) {
    const float* x  = (const float*)d_in[0];
    const float* W1 = (const float*)d_in[1];
    const float* b1 = (const float*)d_in[2];
    const float* W2 = (const float*)d_in[3];
    const float* b2 = (const float*)d_in[4];
    float* outs = (float*)d_out;                                   // (T,B,80) spikes
    float* outm = outs + (size_t)T_STEPS * BATCH * N_OUT;          // (T,B,80) mem

    k1_cur1<<<T_STEPS * 4, 256, 0, stream>>>(x, W1, b1, outs);     // cur1 -> outs
    k2_rec1<<<BATCH, 64, 0, stream>>>(outs);                       // spk overwrites cur1
    k3_cur2<<<250 * 4, 256, 0, stream>>>(outs, W2, b2, outm);      // cur2 -> outm
    k4_rec2<<<BATCH, 80, 0, stream>>>(outm, outs);                 // finals in place
}

// Round 14
// 127.538 us; speedup vs baseline: 1.3997x; 1.3997x over previous
//
#include <hip/hip_runtime.h>

// SNN classifier: T=500, B=256, 96 -> 64 -> 80, leaky (subtract reset).
// f32 BLAS-order arithmetic replicated exactly (single-accumulator
// k-ascending __fmaf_rn chains; fixed leaky op-sequence) -> outputs
// bitwise-identical to the passing round-2..13 kernels.
//
// Round-14 = round-11 (best known, 103us) + ONE change: halve/quarter the
// SHARED W operand in LDS and restage it from L2 between phases, instead
// of halving the PRIVATE x/spk tiles (round 13's mistake: private-tile
// halving + direct partial writes thrashed HBM, FETCH 155MB).
//   K1: x[64][100] full 25.6KB + W1-half [48][64] 12.3KB = 37.9KB
//       -> 4 blocks/CU (was 3). W restaged once from L2 (~free, shared).
//   K3: spk 2x[64][68] full 34.8KB + W2-quarter [16][80] 5.1KB = 39.9KB
//       -> 4 blocks/CU (was 2). W restaged 3x from L2.
// Private tiles staged ONCE, exactly like round 11 (FETCH was clean).
// k ascends across phases -> identical FP chains. K2/K4 untouched.

#define T_STEPS 500
#define BATCH   256
#define N_IN    96
#define N_HID   64
#define N_OUT   80
#define CH      50    // chunk size in K2/K4 (500 = 10*50)

// ---------------- K1: cur1 = x @ W1 + b1 ----------------
// grid 500*4, block 256 (4 waves = 4 16-h slices). Block = (t, 64-b group).
__global__ __launch_bounds__(256) void k1_cur1(
    const float* __restrict__ x,   // (T,B,96)
    const float* __restrict__ W1,  // (96,64)
    const float* __restrict__ b1,  // (64)
    float* __restrict__ cur1)      // (T,B,64) region inside outs
{
    const int t    = blockIdx.x >> 2;
    const int b0   = (blockIdx.x & 3) << 6;
    const int lane = threadIdx.x & 63;   // = local b
    const int w    = threadIdx.x >> 6;   // wave id = h-quarter
    const int o0   = w << 4;

    __shared__ float xs[64 * 100];       // x tile, stride 100 (25.6 KB)
    __shared__ float ws[48 * 64];        // W1 half (12.3 KB)

    // ---- stage x full tile (once, coalesced) + W1 half 0
    {
        const float4* __restrict__ src =
            reinterpret_cast<const float4*>(x + ((size_t)t * BATCH + b0) * N_IN);
        #pragma unroll
        for (int ii = 0; ii < 6; ++ii) {
            const int i = ii * 256 + threadIdx.x;
            const float4 v = src[i];
            const int row = i / 24, g = i % 24;
            *reinterpret_cast<float4*>(&xs[row * 100 + g * 4]) = v;
        }
        const float4* __restrict__ srcw = reinterpret_cast<const float4*>(W1);
        #pragma unroll
        for (int ii = 0; ii < 3; ++ii) {
            const int i = ii * 256 + threadIdx.x;   // 768 f4 = rows 0..47
            *reinterpret_cast<float4*>(&ws[i * 4]) = srcw[i];
        }
    }
    __syncthreads();

    float acc[16];
    #pragma unroll
    for (int o = 0; o < 16; ++o) acc[o] = 0.0f;

    #pragma unroll 1
    for (int kh = 0; kh < 2; ++kh) {     // two 48-k phases, k ascending
        #pragma unroll
        for (int kg = 0; kg < 12; ++kg) {
            const int kg_g = kh * 12 + kg;
            const float4 xv = *reinterpret_cast<const float4*>(
                &xs[lane * 100 + kg_g * 4]);
            const float xq[4] = {xv.x, xv.y, xv.z, xv.w};
            #pragma unroll
            for (int j = 0; j < 4; ++j) {
                const int kl = kg * 4 + j;            // local W row 0..47
                const float4* __restrict__ wr =       // LDS broadcast
                    reinterpret_cast<const float4*>(&ws[kl * 64 + o0]);
                const float4 w0 = wr[0], w1 = wr[1], w2 = wr[2], w3 = wr[3];
                const float wv[16] = {w0.x, w0.y, w0.z, w0.w,
                                      w1.x, w1.y, w1.z, w1.w,
                                      w2.x, w2.y, w2.z, w2.w,
                                      w3.x, w3.y, w3.z, w3.w};
                const float xsc = xq[j];
                #pragma unroll
                for (int o = 0; o < 16; ++o)
                    acc[o] = __fmaf_rn(xsc, wv[o], acc[o]);
            }
        }
        if (kh == 0) {                   // restage W1 half 1 (rows 48..95, L2-hot)
            __syncthreads();
            const float4* __restrict__ srcw =
                reinterpret_cast<const float4*>(W1) + 768;
            #pragma unroll
            for (int ii = 0; ii < 3; ++ii) {
                const int i = ii * 256 + threadIdx.x;
                *reinterpret_cast<float4*>(&ws[i * 4]) = srcw[i];
            }
            __syncthreads();
        }
    }

    // ---- bias, transpose via LDS (reuse xs), linear block store (round 11)
    __syncthreads();                     // all xs reads done
    #pragma unroll
    for (int o4 = 0; o4 < 4; ++o4) {
        float4 v;
        v.x = __fadd_rn(acc[o4 * 4 + 0], b1[o0 + o4 * 4 + 0]);
        v.y = __fadd_rn(acc[o4 * 4 + 1], b1[o0 + o4 * 4 + 1]);
        v.z = __fadd_rn(acc[o4 * 4 + 2], b1[o0 + o4 * 4 + 2]);
        v.w = __fadd_rn(acc[o4 * 4 + 3], b1[o0 + o4 * 4 + 3]);
        *reinterpret_cast<float4*>(&xs[lane * 68 + o0 + o4 * 4]) = v;
    }
    __syncthreads();
    {
        float4* __restrict__ dst =
            reinterpret_cast<float4*>(cur1 + ((size_t)t * BATCH + b0) * N_HID);
        #pragma unroll
        for (int ii = 0; ii < 4; ++ii) {
            const int i = ii * 256 + threadIdx.x;
            const int row = i / 16, g = i % 16;
            dst[i] = *reinterpret_cast<const float4*>(&xs[row * 68 + g * 4]);
        }
    }
}

// ---------------- K2: layer-1 recurrence (in-place cur1 -> spk) ----------------
__global__ __launch_bounds__(64) void k2_rec1(float* cs)  // outs region
{
    const int b = blockIdx.x;
    const int h = threadIdx.x;
    const size_t str  = (size_t)BATCH * N_HID;
    const size_t base = (size_t)b * N_HID + h;

    float A[CH], Bv[CH];
    #pragma unroll
    for (int i = 0; i < CH; ++i) A[i] = cs[(size_t)i * str + base];

    float mem = 0.f, s = 0.f;
    for (int cp = 0; cp < 5; ++cp) {            // 10 chunks, processed in pairs
        const int c0 = 2 * cp;
        #pragma unroll
        for (int i = 0; i < CH; ++i)            // prefetch chunk c0+1
            Bv[i] = cs[(size_t)((c0 + 1) * CH + i) * str + base];
        #pragma unroll
        for (int i = 0; i < CH; ++i) {          // compute chunk c0 from A
            const float m = __fsub_rn(__fadd_rn(__fmul_rn(0.95f, mem), A[i]), s);
            mem = m; s = (m > 1.0f) ? 1.0f : 0.0f;
            cs[(size_t)(c0 * CH + i) * str + base] = s;
        }
        if (cp < 4) {
            #pragma unroll
            for (int i = 0; i < CH; ++i)        // prefetch chunk c0+2
                A[i] = cs[(size_t)((c0 + 2) * CH + i) * str + base];
        }
        #pragma unroll
        for (int i = 0; i < CH; ++i) {          // compute chunk c0+1 from Bv
            const float m = __fsub_rn(__fadd_rn(__fmul_rn(0.95f, mem), Bv[i]), s);
            mem = m; s = (m > 1.0f) ? 1.0f : 0.0f;
            cs[(size_t)((c0 + 1) * CH + i) * str + base] = s;
        }
    }
}

// ---------------- K3: cur2 = spk @ W2 + b2 ----------------
// grid 250*4, block 256 (4 waves = 4 20-o slices). Block = (t-pair, 64-b).
__global__ __launch_bounds__(256) void k3_cur2(
    const float* __restrict__ spk,  // (T,B,64) in outs
    const float* __restrict__ W2,   // (64,80)
    const float* __restrict__ b2,   // (80)
    float* __restrict__ cur2)       // (T,B,80) = outm region
{
    const int tp   = blockIdx.x >> 2;
    const int b0   = (blockIdx.x & 3) << 6;
    const int t0   = tp * 2;
    const int lane = threadIdx.x & 63;   // = local b
    const int w    = threadIdx.x >> 6;   // wave id
    const int o0   = w * 20;

    __shared__ float xs0[64 * 68];       // spk t0 full row (17.4 KB)
    __shared__ float xs1[64 * 68];       // spk t0+1 full row
    __shared__ float ws[16 * 80];        // W2 quarter (5.1 KB)

    // ---- stage both spk tiles fully (once, coalesced) + W2 quarter 0
    {
        const float4* __restrict__ s0 =
            reinterpret_cast<const float4*>(spk + ((size_t)t0 * BATCH + b0) * N_HID);
        const float4* __restrict__ s1 =
            reinterpret_cast<const float4*>(spk + ((size_t)(t0 + 1) * BATCH + b0) * N_HID);
        #pragma unroll
        for (int ii = 0; ii < 4; ++ii) {
            const int i = ii * 256 + threadIdx.x;   // 1024 f4 per t
            const float4 v0 = s0[i], v1 = s1[i];
            const int row = i >> 4, g = i & 15;
            *reinterpret_cast<float4*>(&xs0[row * 68 + g * 4]) = v0;
            *reinterpret_cast<float4*>(&xs1[row * 68 + g * 4]) = v1;
        }
        const float4* __restrict__ srcw = reinterpret_cast<const float4*>(W2);
        for (int i = threadIdx.x; i < 320; i += 256)
            *reinterpret_cast<float4*>(&ws[i * 4]) = srcw[i];
    }
    __syncthreads();

    float acc0[20], acc1[20];
    #pragma unroll
    for (int o = 0; o < 20; ++o) { acc0[o] = 0.0f; acc1[o] = 0.0f; }

    #pragma unroll 1
    for (int q = 0; q < 4; ++q) {        // four 16-k phases, k ascending
        #pragma unroll
        for (int kg = 0; kg < 4; ++kg) {
            const int kg_g = q * 4 + kg;
            const float4 xv0 = *reinterpret_cast<const float4*>(
                &xs0[lane * 68 + kg_g * 4]);
            const float4 xv1 = *reinterpret_cast<const float4*>(
                &xs1[lane * 68 + kg_g * 4]);
            const float xq0[4] = {xv0.x, xv0.y, xv0.z, xv0.w};
            const float xq1[4] = {xv1.x, xv1.y, xv1.z, xv1.w};
            #pragma unroll
            for (int j = 0; j < 4; ++j) {
                const int kl = kg * 4 + j;            // local W row 0..15
                const float4* __restrict__ wr =       // LDS broadcast
                    reinterpret_cast<const float4*>(&ws[kl * 80 + o0]);
                const float4 w0 = wr[0], w1 = wr[1], w2 = wr[2], w3 = wr[3], w4 = wr[4];
                const float wv[20] = {w0.x, w0.y, w0.z, w0.w,
                                      w1.x, w1.y, w1.z, w1.w,
                                      w2.x, w2.y, w2.z, w2.w,
                                      w3.x, w3.y, w3.z, w3.w,
                                      w4.x, w4.y, w4.z, w4.w};
                const float a = xq0[j], bb = xq1[j];
                #pragma unroll
                for (int o = 0; o < 20; ++o) {
                    acc0[o] = __fmaf_rn(a,  wv[o], acc0[o]);
                    acc1[o] = __fmaf_rn(bb, wv[o], acc1[o]);
                }
            }
        }
        if (q < 3) {                     // restage next W2 quarter (L2-hot)
            __syncthreads();
            const float4* __restrict__ srcw =
                reinterpret_cast<const float4*>(W2) + (q + 1) * 320;
            for (int i = threadIdx.x; i < 320; i += 256)
                *reinterpret_cast<float4*>(&ws[i * 4]) = srcw[i];
            __syncthreads();
        }
    }

    // ---- bias + direct per-lane stores (clean in round 12: FETCH 16MB)
    float* d0 = cur2 + ((size_t)t0 * BATCH + b0 + lane) * N_OUT + o0;
    float* d1 = cur2 + ((size_t)(t0 + 1) * BATCH + b0 + lane) * N_OUT + o0;
    #pragma unroll
    for (int o4 = 0; o4 < 5; ++o4) {
        float4 v0, v1;
        v0.x = __fadd_rn(acc0[o4 * 4 + 0], b2[o0 + o4 * 4 + 0]);
        v0.y = __fadd_rn(acc0[o4 * 4 + 1], b2[o0 + o4 * 4 + 1]);
        v0.z = __fadd_rn(acc0[o4 * 4 + 2], b2[o0 + o4 * 4 + 2]);
        v0.w = __fadd_rn(acc0[o4 * 4 + 3], b2[o0 + o4 * 4 + 3]);
        v1.x = __fadd_rn(acc1[o4 * 4 + 0], b2[o0 + o4 * 4 + 0]);
        v1.y = __fadd_rn(acc1[o4 * 4 + 1], b2[o0 + o4 * 4 + 1]);
        v1.z = __fadd_rn(acc1[o4 * 4 + 2], b2[o0 + o4 * 4 + 2]);
        v1.w = __fadd_rn(acc1[o4 * 4 + 3], b2[o0 + o4 * 4 + 3]);
        reinterpret_cast<float4*>(d0)[o4] = v0;
        reinterpret_cast<float4*>(d1)[o4] = v1;
    }
}

// ---------------- K4: layer-2 recurrence (cur2 in outm -> spk/mem finals) ----------------
__global__ __launch_bounds__(80) void k4_rec2(float* cm, float* os)
{
    const int b = blockIdx.x;
    const int o = threadIdx.x;   // 0..79
    const size_t str  = (size_t)BATCH * N_OUT;
    const size_t base = (size_t)b * N_OUT + o;

    float A[CH], Bv[CH];
    #pragma unroll
    for (int i = 0; i < CH; ++i) A[i] = cm[(size_t)i * str + base];

    float mem = 0.f, s = 0.f;
    for (int cp = 0; cp < 5; ++cp) {
        const int c0 = 2 * cp;
        #pragma unroll
        for (int i = 0; i < CH; ++i)
            Bv[i] = cm[(size_t)((c0 + 1) * CH + i) * str + base];
        #pragma unroll
        for (int i = 0; i < CH; ++i) {
            const int t = c0 * CH + i;
            const float m = __fsub_rn(__fadd_rn(__fmul_rn(0.95f, mem), A[i]), s);
            mem = m; s = (m > 1.0f) ? 1.0f : 0.0f;
            os[(size_t)t * str + base] = s;
            cm[(size_t)t * str + base] = m;
        }
        if (cp < 4) {
            #pragma unroll
            for (int i = 0; i < CH; ++i)
                A[i] = cm[(size_t)((c0 + 2) * CH + i) * str + base];
        }
        #pragma unroll
        for (int i = 0; i < CH; ++i) {
            const int t = (c0 + 1) * CH + i;
            const float m = __fsub_rn(__fadd_rn(__fmul_rn(0.95f, mem), Bv[i]), s);
            mem = m; s = (m > 1.0f) ? 1.0f : 0.0f;
            os[(size_t)t * str + base] = s;
            cm[(size_t)t * str + base] = m;
        }
    }
}

extern "C" void kernel_launch(void* const* d_in, const int* in_sizes, int n_in,
                              void* d_out, int out_size, void* d_ws, size_t ws_size,
                              hipStream_t stream) {
    const float* x  = (const float*)d_in[0];
    const float* W1 = (const float*)d_in[1];
    const float* b1 = (const float*)d_in[2];
    const float* W2 = (const float*)d_in[3];
    const float* b2 = (const float*)d_in[4];
    float* outs = (float*)d_out;                                   // (T,B,80) spikes
    float* outm = outs + (size_t)T_STEPS * BATCH * N_OUT;          // (T,B,80) mem

    k1_cur1<<<T_STEPS * 4, 256, 0, stream>>>(x, W1, b1, outs);     // cur1 -> outs
    k2_rec1<<<BATCH, 64, 0, stream>>>(outs);                       // spk overwrites cur1
    k3_cur2<<<250 * 4, 256, 0, stream>>>(outs, W2, b2, outm);      // cur2 -> outm
    k4_rec2<<<BATCH, 80, 0, stream>>>(outm, outs);                 // finals in place
}

// Round 16
// 97.046 us; speedup vs baseline: 1.8394x; 1.3142x over previous
//
#include <hip/hip_runtime.h>

// SNN classifier: T=500, B=256, 96 -> 64 -> 80, leaky (subtract reset).
// f32 BLAS-order arithmetic replicated exactly (single-accumulator
// k-ascending __fmaf_rn chains; fixed leaky op-sequence) -> outputs
// bitwise-identical to the passing round-2..14 kernels.
//
// Round-16: R15's b-pair K3 had an LDS stride bug (64-float rows staged at
// stride 36 -> row overlap) - discarded. DS-throughput model (12cyc/b128,
// m134) fits R11 exactly (K1 64us, K3 27us): these kernels are bound by
// DS-instruction count, which amortizes only over rows-per-lane P.
// This round: K1 -> P=2 via t-pairing, single-phase staging (no restage:
// R12/R14 failure modes avoided), 75.8KB static LDS (gfx950 allows >64KB
// per workgroup; guide's m201 template uses 128KB plain-HIP). 2 blocks/CU.
// W-broadcast count per output halves. K3 = round-11 VERBATIM. K2/K4
// verbatim. Chains unchanged -> bitwise-identical.

#define T_STEPS 500
#define BATCH   256
#define N_IN    96
#define N_HID   64
#define N_OUT   80
#define CH      50    // chunk size in K2/K4 (500 = 10*50)

// ---------------- K1: cur1 = x @ W1 + b1 ----------------
// grid 250*4, block 256 (4 waves = 4 h-quarters). Block = (t-pair, 64-b).
// LDS: x t0 [64][100] @0, x t1 @6400, W1 [96][64] @12800 = 18944 fl = 75.8KB.
__global__ __launch_bounds__(256) void k1_cur1(
    const float* __restrict__ x,   // (T,B,96)
    const float* __restrict__ W1,  // (96,64)
    const float* __restrict__ b1,  // (64)
    float* __restrict__ cur1)      // (T,B,64) region inside outs
{
    const int tp   = blockIdx.x >> 2;        // 0..249
    const int b0   = (blockIdx.x & 3) << 6;
    const int t0   = tp * 2;
    const int lane = threadIdx.x & 63;       // = local b
    const int w    = threadIdx.x >> 6;       // wave id = h-quarter
    const int o0   = w << 4;

    __shared__ float sm[18944];              // 75.8 KB (gfx950: 160KB/CU)

    // ---- stage both x tiles + full W1 (all coalesced, single phase)
    {
        const float4* __restrict__ s0 =
            reinterpret_cast<const float4*>(x + ((size_t)t0 * BATCH + b0) * N_IN);
        const float4* __restrict__ s1 =
            reinterpret_cast<const float4*>(x + ((size_t)(t0 + 1) * BATCH + b0) * N_IN);
        #pragma unroll
        for (int ii = 0; ii < 6; ++ii) {
            const int i = ii * 256 + threadIdx.x;
            const float4 v0 = s0[i], v1 = s1[i];
            const int row = i / 24, g = i % 24;
            *reinterpret_cast<float4*>(&sm[row * 100 + g * 4]) = v0;
            *reinterpret_cast<float4*>(&sm[6400 + row * 100 + g * 4]) = v1;
        }
        const float4* __restrict__ srcw = reinterpret_cast<const float4*>(W1);
        #pragma unroll
        for (int ii = 0; ii < 6; ++ii) {
            const int i = ii * 256 + threadIdx.x;
            *reinterpret_cast<float4*>(&sm[12800 + i * 4]) = srcw[i];
        }
    }
    __syncthreads();

    float acc0[16], acc1[16];
    #pragma unroll
    for (int o = 0; o < 16; ++o) { acc0[o] = 0.0f; acc1[o] = 0.0f; }

    const int xb = lane * 100;
    #pragma unroll 2
    for (int kg = 0; kg < 24; ++kg) {
        const float4 xv0 = *reinterpret_cast<const float4*>(&sm[xb + kg * 4]);
        const float4 xv1 = *reinterpret_cast<const float4*>(&sm[6400 + xb + kg * 4]);
        const float xq0[4] = {xv0.x, xv0.y, xv0.z, xv0.w};
        const float xq1[4] = {xv1.x, xv1.y, xv1.z, xv1.w};
        #pragma unroll
        for (int jj = 0; jj < 4; ++jj) {
            const int k = kg * 4 + jj;
            const float4* __restrict__ wr =                 // LDS broadcast
                reinterpret_cast<const float4*>(&sm[12800 + k * 64 + o0]);
            const float4 w0 = wr[0], w1 = wr[1], w2 = wr[2], w3 = wr[3];
            const float xs0 = xq0[jj], xs1 = xq1[jj];
            acc0[0]  = __fmaf_rn(xs0, w0.x, acc0[0]);
            acc0[1]  = __fmaf_rn(xs0, w0.y, acc0[1]);
            acc0[2]  = __fmaf_rn(xs0, w0.z, acc0[2]);
            acc0[3]  = __fmaf_rn(xs0, w0.w, acc0[3]);
            acc0[4]  = __fmaf_rn(xs0, w1.x, acc0[4]);
            acc0[5]  = __fmaf_rn(xs0, w1.y, acc0[5]);
            acc0[6]  = __fmaf_rn(xs0, w1.z, acc0[6]);
            acc0[7]  = __fmaf_rn(xs0, w1.w, acc0[7]);
            acc0[8]  = __fmaf_rn(xs0, w2.x, acc0[8]);
            acc0[9]  = __fmaf_rn(xs0, w2.y, acc0[9]);
            acc0[10] = __fmaf_rn(xs0, w2.z, acc0[10]);
            acc0[11] = __fmaf_rn(xs0, w2.w, acc0[11]);
            acc0[12] = __fmaf_rn(xs0, w3.x, acc0[12]);
            acc0[13] = __fmaf_rn(xs0, w3.y, acc0[13]);
            acc0[14] = __fmaf_rn(xs0, w3.z, acc0[14]);
            acc0[15] = __fmaf_rn(xs0, w3.w, acc0[15]);
            acc1[0]  = __fmaf_rn(xs1, w0.x, acc1[0]);
            acc1[1]  = __fmaf_rn(xs1, w0.y, acc1[1]);
            acc1[2]  = __fmaf_rn(xs1, w0.z, acc1[2]);
            acc1[3]  = __fmaf_rn(xs1, w0.w, acc1[3]);
            acc1[4]  = __fmaf_rn(xs1, w1.x, acc1[4]);
            acc1[5]  = __fmaf_rn(xs1, w1.y, acc1[5]);
            acc1[6]  = __fmaf_rn(xs1, w1.z, acc1[6]);
            acc1[7]  = __fmaf_rn(xs1, w1.w, acc1[7]);
            acc1[8]  = __fmaf_rn(xs1, w2.x, acc1[8]);
            acc1[9]  = __fmaf_rn(xs1, w2.y, acc1[9]);
            acc1[10] = __fmaf_rn(xs1, w2.z, acc1[10]);
            acc1[11] = __fmaf_rn(xs1, w2.w, acc1[11]);
            acc1[12] = __fmaf_rn(xs1, w3.x, acc1[12]);
            acc1[13] = __fmaf_rn(xs1, w3.y, acc1[13]);
            acc1[14] = __fmaf_rn(xs1, w3.z, acc1[14]);
            acc1[15] = __fmaf_rn(xs1, w3.w, acc1[15]);
        }
    }

    // ---- bias, transpose both t's via LDS (reuse x areas), linear stores
    __syncthreads();                     // all x/W reads done
    #pragma unroll
    for (int o4 = 0; o4 < 4; ++o4) {
        float4 v0, v1;
        v0.x = __fadd_rn(acc0[o4 * 4 + 0], b1[o0 + o4 * 4 + 0]);
        v0.y = __fadd_rn(acc0[o4 * 4 + 1], b1[o0 + o4 * 4 + 1]);
        v0.z = __fadd_rn(acc0[o4 * 4 + 2], b1[o0 + o4 * 4 + 2]);
        v0.w = __fadd_rn(acc0[o4 * 4 + 3], b1[o0 + o4 * 4 + 3]);
        v1.x = __fadd_rn(acc1[o4 * 4 + 0], b1[o0 + o4 * 4 + 0]);
        v1.y = __fadd_rn(acc1[o4 * 4 + 1], b1[o0 + o4 * 4 + 1]);
        v1.z = __fadd_rn(acc1[o4 * 4 + 2], b1[o0 + o4 * 4 + 2]);
        v1.w = __fadd_rn(acc1[o4 * 4 + 3], b1[o0 + o4 * 4 + 3]);
        *reinterpret_cast<float4*>(&sm[lane * 68 + o0 + o4 * 4]) = v0;
        *reinterpret_cast<float4*>(&sm[6400 + lane * 68 + o0 + o4 * 4]) = v1;
    }
    __syncthreads();
    {
        float4* __restrict__ d0 =
            reinterpret_cast<float4*>(cur1 + ((size_t)t0 * BATCH + b0) * N_HID);
        float4* __restrict__ d1 =
            reinterpret_cast<float4*>(cur1 + ((size_t)(t0 + 1) * BATCH + b0) * N_HID);
        #pragma unroll
        for (int ii = 0; ii < 4; ++ii) {
            const int i = ii * 256 + threadIdx.x;
            const int row = i / 16, g = i % 16;
            d0[i] = *reinterpret_cast<const float4*>(&sm[row * 68 + g * 4]);
            d1[i] = *reinterpret_cast<const float4*>(&sm[6400 + row * 68 + g * 4]);
        }
    }
}

// ---------------- K2: layer-1 recurrence (in-place cur1 -> spk) ----------------
__global__ __launch_bounds__(64) void k2_rec1(float* cs)  // outs region
{
    const int b = blockIdx.x;
    const int h = threadIdx.x;
    const size_t str  = (size_t)BATCH * N_HID;
    const size_t base = (size_t)b * N_HID + h;

    float A[CH], Bv[CH];
    #pragma unroll
    for (int i = 0; i < CH; ++i) A[i] = cs[(size_t)i * str + base];

    float mem = 0.f, s = 0.f;
    for (int cp = 0; cp < 5; ++cp) {            // 10 chunks, processed in pairs
        const int c0 = 2 * cp;
        #pragma unroll
        for (int i = 0; i < CH; ++i)            // prefetch chunk c0+1
            Bv[i] = cs[(size_t)((c0 + 1) * CH + i) * str + base];
        #pragma unroll
        for (int i = 0; i < CH; ++i) {          // compute chunk c0 from A
            const float m = __fsub_rn(__fadd_rn(__fmul_rn(0.95f, mem), A[i]), s);
            mem = m; s = (m > 1.0f) ? 1.0f : 0.0f;
            cs[(size_t)(c0 * CH + i) * str + base] = s;
        }
        if (cp < 4) {
            #pragma unroll
            for (int i = 0; i < CH; ++i)        // prefetch chunk c0+2
                A[i] = cs[(size_t)((c0 + 2) * CH + i) * str + base];
        }
        #pragma unroll
        for (int i = 0; i < CH; ++i) {          // compute chunk c0+1 from Bv
            const float m = __fsub_rn(__fadd_rn(__fmul_rn(0.95f, mem), Bv[i]), s);
            mem = m; s = (m > 1.0f) ? 1.0f : 0.0f;
            cs[(size_t)((c0 + 1) * CH + i) * str + base] = s;
        }
    }
}

// ---------------- K3: cur2 = spk @ W2 + b2 ---------------- (round-11 verbatim)
// grid 250*4, block 256 (4 waves = 4 20-o slices). Block = (t-pair, 64-b).
// LDS: spk 2x[64][68] @0 (8704 dw) + W2 [64][80] @8704 (5120 dw) = 55.3 KB.
__global__ __launch_bounds__(256) void k3_cur2(
    const float* __restrict__ spk,  // (T,B,64) in outs
    const float* __restrict__ W2,   // (64,80)
    const float* __restrict__ b2,   // (80)
    float* __restrict__ cur2)       // (T,B,80) = outm region
{
    const int tp   = blockIdx.x >> 2;
    const int b0   = (blockIdx.x & 3) << 6;
    const int t0   = tp * 2;
    const int lane = threadIdx.x & 63;   // = local b
    const int w    = threadIdx.x >> 6;   // wave id
    const int o0   = w * 20;

    __shared__ float sm[13824];          // 55.3 KB

    // ---- stage spk tiles (coalesced) + full W2 (coalesced, linear)
    {
        const float4* __restrict__ s0 =
            reinterpret_cast<const float4*>(spk + ((size_t)t0 * BATCH + b0) * N_HID);
        const float4* __restrict__ s1 =
            reinterpret_cast<const float4*>(spk + ((size_t)(t0 + 1) * BATCH + b0) * N_HID);
        #pragma unroll
        for (int ii = 0; ii < 4; ++ii) {
            const int i = ii * 256 + threadIdx.x;
            const float4 v0 = s0[i], v1 = s1[i];
            const int row = i / 16, g = i % 16;
            *reinterpret_cast<float4*>(&sm[row * 68 + g * 4]) = v0;
            *reinterpret_cast<float4*>(&sm[4352 + row * 68 + g * 4]) = v1;
        }
        const float4* __restrict__ srcw = reinterpret_cast<const float4*>(W2);
        for (int i = threadIdx.x; i < 1280; i += 256)
            *reinterpret_cast<float4*>(&sm[8704 + i * 4]) = srcw[i];
    }
    __syncthreads();

    float acc0[20], acc1[20];
    #pragma unroll
    for (int o = 0; o < 20; ++o) { acc0[o] = 0.0f; acc1[o] = 0.0f; }

    const int xb0 = lane * 68;
    const int xb1 = 4352 + lane * 68;
    #pragma unroll 2
    for (int kg = 0; kg < 16; ++kg) {
        const float4 xv0 = *reinterpret_cast<const float4*>(&sm[xb0 + kg * 4]);
        const float4 xv1 = *reinterpret_cast<const float4*>(&sm[xb1 + kg * 4]);
        const float xq0[4] = {xv0.x, xv0.y, xv0.z, xv0.w};
        const float xq1[4] = {xv1.x, xv1.y, xv1.z, xv1.w};
        #pragma unroll
        for (int jj = 0; jj < 4; ++jj) {
            const int k = kg * 4 + jj;
            const float4* __restrict__ wr =                 // LDS broadcast
                reinterpret_cast<const float4*>(&sm[8704 + k * 80 + o0]);
            const float4 w0 = wr[0], w1 = wr[1], w2 = wr[2], w3 = wr[3], w4 = wr[4];
            const float a = xq0[jj], b = xq1[jj];
            acc0[0]  = __fmaf_rn(a, w0.x, acc0[0]);
            acc0[1]  = __fmaf_rn(a, w0.y, acc0[1]);
            acc0[2]  = __fmaf_rn(a, w0.z, acc0[2]);
            acc0[3]  = __fmaf_rn(a, w0.w, acc0[3]);
            acc0[4]  = __fmaf_rn(a, w1.x, acc0[4]);
            acc0[5]  = __fmaf_rn(a, w1.y, acc0[5]);
            acc0[6]  = __fmaf_rn(a, w1.z, acc0[6]);
            acc0[7]  = __fmaf_rn(a, w1.w, acc0[7]);
            acc0[8]  = __fmaf_rn(a, w2.x, acc0[8]);
            acc0[9]  = __fmaf_rn(a, w2.y, acc0[9]);
            acc0[10] = __fmaf_rn(a, w2.z, acc0[10]);
            acc0[11] = __fmaf_rn(a, w2.w, acc0[11]);
            acc0[12] = __fmaf_rn(a, w3.x, acc0[12]);
            acc0[13] = __fmaf_rn(a, w3.y, acc0[13]);
            acc0[14] = __fmaf_rn(a, w3.z, acc0[14]);
            acc0[15] = __fmaf_rn(a, w3.w, acc0[15]);
            acc0[16] = __fmaf_rn(a, w4.x, acc0[16]);
            acc0[17] = __fmaf_rn(a, w4.y, acc0[17]);
            acc0[18] = __fmaf_rn(a, w4.z, acc0[18]);
            acc0[19] = __fmaf_rn(a, w4.w, acc0[19]);
            acc1[0]  = __fmaf_rn(b, w0.x, acc1[0]);
            acc1[1]  = __fmaf_rn(b, w0.y, acc1[1]);
            acc1[2]  = __fmaf_rn(b, w0.z, acc1[2]);
            acc1[3]  = __fmaf_rn(b, w0.w, acc1[3]);
            acc1[4]  = __fmaf_rn(b, w1.x, acc1[4]);
            acc1[5]  = __fmaf_rn(b, w1.y, acc1[5]);
            acc1[6]  = __fmaf_rn(b, w1.z, acc1[6]);
            acc1[7]  = __fmaf_rn(b, w1.w, acc1[7]);
            acc1[8]  = __fmaf_rn(b, w2.x, acc1[8]);
            acc1[9]  = __fmaf_rn(b, w2.y, acc1[9]);
            acc1[10] = __fmaf_rn(b, w2.z, acc1[10]);
            acc1[11] = __fmaf_rn(b, w2.w, acc1[11]);
            acc1[12] = __fmaf_rn(b, w3.x, acc1[12]);
            acc1[13] = __fmaf_rn(b, w3.y, acc1[13]);
            acc1[14] = __fmaf_rn(b, w3.z, acc1[14]);
            acc1[15] = __fmaf_rn(b, w3.w, acc1[15]);
            acc1[16] = __fmaf_rn(b, w4.x, acc1[16]);
            acc1[17] = __fmaf_rn(b, w4.y, acc1[17]);
            acc1[18] = __fmaf_rn(b, w4.z, acc1[18]);
            acc1[19] = __fmaf_rn(b, w4.w, acc1[19]);
        }
    }

    // ---- bias, transpose via LDS, linear block stores
    __syncthreads();                     // all spk/W reads done
    #pragma unroll
    for (int o4 = 0; o4 < 5; ++o4) {
        float4 v0, v1;
        v0.x = __fadd_rn(acc0[o4 * 4 + 0], b2[o0 + o4 * 4 + 0]);
        v0.y = __fadd_rn(acc0[o4 * 4 + 1], b2[o0 + o4 * 4 + 1]);
        v0.z = __fadd_rn(acc0[o4 * 4 + 2], b2[o0 + o4 * 4 + 2]);
        v0.w = __fadd_rn(acc0[o4 * 4 + 3], b2[o0 + o4 * 4 + 3]);
        v1.x = __fadd_rn(acc1[o4 * 4 + 0], b2[o0 + o4 * 4 + 0]);
        v1.y = __fadd_rn(acc1[o4 * 4 + 1], b2[o0 + o4 * 4 + 1]);
        v1.z = __fadd_rn(acc1[o4 * 4 + 2], b2[o0 + o4 * 4 + 2]);
        v1.w = __fadd_rn(acc1[o4 * 4 + 3], b2[o0 + o4 * 4 + 3]);
        *reinterpret_cast<float4*>(&sm[lane * 84 + o0 + o4 * 4]) = v0;
        *reinterpret_cast<float4*>(&sm[5376 + lane * 84 + o0 + o4 * 4]) = v1;
    }
    __syncthreads();
    {
        float4* __restrict__ d0 =
            reinterpret_cast<float4*>(cur2 + ((size_t)t0 * BATCH + b0) * N_OUT);
        float4* __restrict__ d1 =
            reinterpret_cast<float4*>(cur2 + ((size_t)(t0 + 1) * BATCH + b0) * N_OUT);
        #pragma unroll
        for (int ii = 0; ii < 5; ++ii) {
            const int i = ii * 256 + threadIdx.x;
            const int row = i / 20, g = i % 20;
            d0[i] = *reinterpret_cast<const float4*>(&sm[row * 84 + g * 4]);
            d1[i] = *reinterpret_cast<const float4*>(&sm[5376 + row * 84 + g * 4]);
        }
    }
}

// ---------------- K4: layer-2 recurrence (cur2 in outm -> spk/mem finals) ----------------
__global__ __launch_bounds__(80) void k4_rec2(float* cm, float* os)
{
    const int b = blockIdx.x;
    const int o = threadIdx.x;   // 0..79
    const size_t str  = (size_t)BATCH * N_OUT;
    const size_t base = (size_t)b * N_OUT + o;

    float A[CH], Bv[CH];
    #pragma unroll
    for (int i = 0; i < CH; ++i) A[i] = cm[(size_t)i * str + base];

    float mem = 0.f, s = 0.f;
    for (int cp = 0; cp < 5; ++cp) {
        const int c0 = 2 * cp;
        #pragma unroll
        for (int i = 0; i < CH; ++i)
            Bv[i] = cm[(size_t)((c0 + 1) * CH + i) * str + base];
        #pragma unroll
        for (int i = 0; i < CH; ++i) {
            const int t = c0 * CH + i;
            const float m = __fsub_rn(__fadd_rn(__fmul_rn(0.95f, mem), A[i]), s);
            mem = m; s = (m > 1.0f) ? 1.0f : 0.0f;
            os[(size_t)t * str + base] = s;
            cm[(size_t)t * str + base] = m;
        }
        if (cp < 4) {
            #pragma unroll
            for (int i = 0; i < CH; ++i)
                A[i] = cm[(size_t)((c0 + 2) * CH + i) * str + base];
        }
        #pragma unroll
        for (int i = 0; i < CH; ++i) {
            const int t = (c0 + 1) * CH + i;
            const float m = __fsub_rn(__fadd_rn(__fmul_rn(0.95f, mem), Bv[i]), s);
            mem = m; s = (m > 1.0f) ? 1.0f : 0.0f;
            os[(size_t)t * str + base] = s;
            cm[(size_t)t * str + base] = m;
        }
    }
}

extern "C" void kernel_launch(void* const* d_in, const int* in_sizes, int n_in,
                              void* d_out, int out_size, void* d_ws, size_t ws_size,
                              hipStream_t stream) {
    const float* x  = (const float*)d_in[0];
    const float* W1 = (const float*)d_in[1];
    const float* b1 = (const float*)d_in[2];
    const float* W2 = (const float*)d_in[3];
    const float* b2 = (const float*)d_in[4];
    float* outs = (float*)d_out;                                   // (T,B,80) spikes
    float* outm = outs + (size_t)T_STEPS * BATCH * N_OUT;          // (T,B,80) mem

    k1_cur1<<<250 * 4, 256, 0, stream>>>(x, W1, b1, outs);         // cur1 -> outs
    k2_rec1<<<BATCH, 64, 0, stream>>>(outs);                       // spk overwrites cur1
    k3_cur2<<<250 * 4, 256, 0, stream>>>(outs, W2, b2, outm);      // cur2 -> outm
    k4_rec2<<<BATCH, 80, 0, stream>>>(outm, outs);                 // finals in place
}